// Round 1
// baseline (99.651 us; speedup 1.0000x reference)
//
#include <hip/hip_runtime.h>
#include <stdint.h>

// ---------------------------------------------------------------------------
// AdditiveAttention (Bahdanau) + gumbel-softmax(tau=0.01), channel 0.
//
// out[b,i,j] = sigmoid( ((s0+g0) - (masked1+g1)) * 100 )
//   s_c       = sum_h tanh(q[b,i,h] + k[b,j,h]) * Wv[c,h]
//   masked1   = s1 if mask==2 else -1e6   (channel 0 never masked, mask>=1)
//   g         = jax.random.gumbel(jax.random.key(42), (B,Lq,Lk,2), f32)
//
// RNG_VARIANT: exact replication of jax threefry random_bits.
//   1 = partitionable (jax >= 0.4.30 default): block (hi=0, lo=flat), o0^o1
//   2 = partitionable, take o0
//   3 = legacy split-iota mode (jax_threefry_partitionable=False)
// ---------------------------------------------------------------------------

#define RNG_VARIANT 1

#define BB 4
#define LLEN 512
#define DD 256
#define HH 128

__device__ __forceinline__ uint32_t rotl32(uint32_t v, int r) {
  return (v << r) | (v >> (32 - r));
}

// Threefry-2x32, key = (0, 42)  [jax.random.key(42) -> (hi,lo)=(0,42)]
__device__ __forceinline__ void tf2x32(uint32_t x0, uint32_t x1,
                                       uint32_t& o0, uint32_t& o1) {
  const uint32_t k0 = 0u;
  const uint32_t k1 = 42u;
  const uint32_t k2 = 0x1BD11BDAu ^ k0 ^ k1;  // 0x1BD11BF0

  x0 += k0; x1 += k1;
#define TFR(r) { x0 += x1; x1 = rotl32(x1, (r)); x1 ^= x0; }
  TFR(13) TFR(15) TFR(26) TFR(6)
  x0 += k1; x1 += k2 + 1u;
  TFR(17) TFR(29) TFR(16) TFR(24)
  x0 += k2; x1 += k0 + 2u;
  TFR(13) TFR(15) TFR(26) TFR(6)
  x0 += k0; x1 += k1 + 3u;
  TFR(17) TFR(29) TFR(16) TFR(24)
  x0 += k1; x1 += k2 + 4u;
  TFR(13) TFR(15) TFR(26) TFR(6)
  x0 += k2; x1 += k0 + 5u;
#undef TFR
  o0 = x0; o1 = x1;
}

__device__ __forceinline__ uint32_t jax_random_bits32(uint32_t flat) {
#if RNG_VARIANT == 1
  uint32_t o0, o1;
  tf2x32(0u, flat, o0, o1);     // counter u64: hi=0 (x0), lo=flat (x1)
  return o0 ^ o1;
#elif RNG_VARIANT == 2
  uint32_t o0, o1;
  tf2x32(0u, flat, o0, o1);
  return o0;
#else
  // legacy: bits = threefry(key, iota(2N)) with iota split in halves
  const uint32_t N = (BB * LLEN * LLEN * 2) / 2;  // 1048576
  uint32_t o0, o1;
  if (flat < N) { tf2x32(flat, flat + N, o0, o1); return o0; }
  else          { tf2x32(flat - N, flat, o0, o1); return o1; }
#endif
}

// jax: u = max(tiny, ((bits>>9)|0x3f800000) - 1.0); g = -log(-log(u))
// NOTE: libm logf (not __logf) — need full relative accuracy for u near 1.
__device__ __forceinline__ float jax_gumbel(uint32_t flat) {
  const uint32_t bits = jax_random_bits32(flat);
  const float f = __uint_as_float((bits >> 9) | 0x3F800000u) - 1.0f;
  const float u = fmaxf(f, 1.17549435e-38f);
  const float L = -logf(u);
  return -logf(L);
}

// tanh via hw exp; abs error ~1e-7, fine for the error budget.
__device__ __forceinline__ float fast_tanh(float x) {
  const float xc = fminf(fmaxf(x, -15.0f), 15.0f);
  const float e = __expf(2.0f * xc);
  return 1.0f - __fdividef(2.0f, e + 1.0f);
}

// ---------------------------------------------------------------------------
// Kernel A: projections.  blocks 0..511 -> Q rows, 512..1023 -> K rows.
// Each block: 4 rows of input staged in LDS; thread h does 256-long dots.
// ---------------------------------------------------------------------------
__global__ __launch_bounds__(128) void proj_kernel(
    const float* __restrict__ queries, const float* __restrict__ keys,
    const float* __restrict__ Wq, const float* __restrict__ Wk,
    float* __restrict__ Qp, float* __restrict__ Kp) {
  const int blk = blockIdx.x;
  const bool isK = blk >= (BB * LLEN / 4);
  const int rb = (isK ? blk - (BB * LLEN / 4) : blk) * 4;  // row base (of 2048)
  const float* __restrict__ in  = isK ? keys : queries;
  const float* __restrict__ W   = isK ? Wk : Wq;
  float* __restrict__ outp      = isK ? Kp : Qp;

  __shared__ float rows[4][DD];
  const float4* in4 = reinterpret_cast<const float4*>(in + (size_t)rb * DD);
  float4* rows4 = reinterpret_cast<float4*>(&rows[0][0]);
  for (int t = threadIdx.x; t < 4 * DD / 4; t += 128) rows4[t] = in4[t];
  __syncthreads();

  const int h = threadIdx.x;
  const float4* W4 = reinterpret_cast<const float4*>(W + (size_t)h * DD);
  float a0 = 0.f, a1 = 0.f, a2 = 0.f, a3 = 0.f;
  #pragma unroll 4
  for (int d4 = 0; d4 < DD / 4; ++d4) {
    const float4 w = W4[d4];
    const int d = d4 * 4;
    a0 = fmaf(w.x, rows[0][d], fmaf(w.y, rows[0][d+1], fmaf(w.z, rows[0][d+2], fmaf(w.w, rows[0][d+3], a0))));
    a1 = fmaf(w.x, rows[1][d], fmaf(w.y, rows[1][d+1], fmaf(w.z, rows[1][d+2], fmaf(w.w, rows[1][d+3], a1))));
    a2 = fmaf(w.x, rows[2][d], fmaf(w.y, rows[2][d+1], fmaf(w.z, rows[2][d+2], fmaf(w.w, rows[2][d+3], a2))));
    a3 = fmaf(w.x, rows[3][d], fmaf(w.y, rows[3][d+1], fmaf(w.z, rows[3][d+2], fmaf(w.w, rows[3][d+3], a3))));
  }
  float* orow = outp + (size_t)rb * HH + h;
  orow[0 * HH] = a0; orow[1 * HH] = a1; orow[2 * HH] = a2; orow[3 * HH] = a3;
}

// ---------------------------------------------------------------------------
// Kernel B: 32x32 output tile per block (grid 16x16x4), 256 threads,
// 4 outputs/thread.  Q/K tiles in LDS as float4 with odd stride 33
// (conflict-free ds_read_b128: 8 consecutive lanes fill all 32 banks).
// ---------------------------------------------------------------------------
__global__ __launch_bounds__(256) void attn_kernel(
    const float* __restrict__ Qp, const float* __restrict__ Kp,
    const int* __restrict__ mask, const float* __restrict__ Wv,
    float* __restrict__ out) {
  __shared__ float4 QL[32][33];
  __shared__ float4 KL[32][33];
  __shared__ float4 WvL[64];  // [0..31]=Wv[0][h], [32..63]=Wv[1][h]

  const int bi = blockIdx.x, bj = blockIdx.y, b = blockIdx.z;
  const int i0 = bi * 32, j0 = bj * 32;

  const float4* Q4 = reinterpret_cast<const float4*>(Qp) + ((size_t)b * LLEN + i0) * (HH / 4);
  const float4* K4 = reinterpret_cast<const float4*>(Kp) + ((size_t)b * LLEN + j0) * (HH / 4);
  for (int t = threadIdx.x; t < 32 * (HH / 4); t += 256) {
    QL[t >> 5][t & 31] = Q4[t];
    KL[t >> 5][t & 31] = K4[t];
  }
  if (threadIdx.x < 64)
    WvL[threadIdx.x] = reinterpret_cast<const float4*>(Wv)[threadIdx.x];
  __syncthreads();

  const int jj = threadIdx.x & 31;   // j within tile
  const int ib = threadIdx.x >> 5;   // i base (0..7); rows ib, ib+8, ib+16, ib+24

  float s0[4] = {0.f, 0.f, 0.f, 0.f};
  float s1[4] = {0.f, 0.f, 0.f, 0.f};

  #pragma unroll 4
  for (int h4 = 0; h4 < HH / 4; ++h4) {
    const float4 kv = KL[jj][h4];
    const float4 w0 = WvL[h4];
    const float4 w1 = WvL[32 + h4];
    #pragma unroll
    for (int r = 0; r < 4; ++r) {
      const float4 qv = QL[ib + 8 * r][h4];
      const float t0 = fast_tanh(qv.x + kv.x);
      const float t1 = fast_tanh(qv.y + kv.y);
      const float t2 = fast_tanh(qv.z + kv.z);
      const float t3 = fast_tanh(qv.w + kv.w);
      s0[r] = fmaf(t0, w0.x, fmaf(t1, w0.y, fmaf(t2, w0.z, fmaf(t3, w0.w, s0[r]))));
      s1[r] = fmaf(t0, w1.x, fmaf(t1, w1.y, fmaf(t2, w1.z, fmaf(t3, w1.w, s1[r]))));
    }
  }

  #pragma unroll
  for (int r = 0; r < 4; ++r) {
    const int i = i0 + ib + 8 * r;
    const int j = j0 + jj;
    const uint32_t idx = ((uint32_t)b * LLEN + i) * LLEN + j;
    const int m = mask[idx];
    const float g0 = jax_gumbel(idx * 2u);
    const float g1 = jax_gumbel(idx * 2u + 1u);
    const float a0 = s0[r] + g0;
    const float a1 = (m >= 2) ? (s1[r] + g1) : (-1000000.0f + g1);
    const float arg = (a0 - a1) * 100.0f;   // (x0 - x1)/tau
    out[idx] = 1.0f / (1.0f + __expf(-arg));  // softmax channel 0
  }
}

extern "C" void kernel_launch(void* const* d_in, const int* in_sizes, int n_in,
                              void* d_out, int out_size, void* d_ws, size_t ws_size,
                              hipStream_t stream) {
  const float* queries = (const float*)d_in[0];
  const float* keys    = (const float*)d_in[1];
  const int*   mask    = (const int*)d_in[2];
  const float* Wq      = (const float*)d_in[3];
  const float* Wk      = (const float*)d_in[4];
  const float* Wv      = (const float*)d_in[5];
  float* out = (float*)d_out;

  // workspace: Qp [2048][128] f32, Kp [2048][128] f32  (2 MB total)
  float* Qp = (float*)d_ws;
  float* Kp = Qp + (size_t)BB * LLEN * HH;

  proj_kernel<<<dim3(2 * (BB * LLEN / 4)), dim3(128), 0, stream>>>(
      queries, keys, Wq, Wk, Qp, Kp);
  attn_kernel<<<dim3(LLEN / 32, LLEN / 32, BB), dim3(256), 0, stream>>>(
      Qp, Kp, mask, Wv, out);
}

// Round 2
// 99.516 us; speedup vs baseline: 1.0014x; 1.0014x over previous
//
#include <hip/hip_runtime.h>
#include <stdint.h>

// ---------------------------------------------------------------------------
// AdditiveAttention (Bahdanau) + gumbel-softmax(tau=0.01), channel 0.
//
// out[b,i,j] = sigmoid( ((s0+g0) - (masked1+g1)) * 100 )
//   s_c       = sum_h tanh(q[b,i,h] + k[b,j,h]) * Wv[c,h]
//   masked1   = s1 if mask==2 else -1e6   (channel 0 never masked, mask>=1)
//   g         = jax.random.gumbel(jax.random.key(42), (B,Lq,Lk,2), f32)
//
// RNG_VARIANT: exact replication of jax threefry random_bits.
//   1 = partitionable (jax >= 0.4.30 default): block (hi=0, lo=flat), o0^o1
//   2 = partitionable, take o0
//   3 = legacy split-iota mode (jax_threefry_partitionable=False)
// ---------------------------------------------------------------------------

#define RNG_VARIANT 1

#define BB 4
#define LLEN 512
#define DD 256
#define HH 128

__device__ __forceinline__ uint32_t rotl32(uint32_t v, int r) {
  return (v << r) | (v >> (32 - r));
}

// Threefry-2x32, key = (0, 42)  [jax.random.key(42) -> (hi,lo)=(0,42)]
__device__ __forceinline__ void tf2x32(uint32_t x0, uint32_t x1,
                                       uint32_t& o0, uint32_t& o1) {
  const uint32_t k0 = 0u;
  const uint32_t k1 = 42u;
  const uint32_t k2 = 0x1BD11BDAu ^ k0 ^ k1;  // 0x1BD11BF0

  x0 += k0; x1 += k1;
#define TFR(r) { x0 += x1; x1 = rotl32(x1, (r)); x1 ^= x0; }
  TFR(13) TFR(15) TFR(26) TFR(6)
  x0 += k1; x1 += k2 + 1u;
  TFR(17) TFR(29) TFR(16) TFR(24)
  x0 += k2; x1 += k0 + 2u;
  TFR(13) TFR(15) TFR(26) TFR(6)
  x0 += k0; x1 += k1 + 3u;
  TFR(17) TFR(29) TFR(16) TFR(24)
  x0 += k1; x1 += k2 + 4u;
  TFR(13) TFR(15) TFR(26) TFR(6)
  x0 += k2; x1 += k0 + 5u;
#undef TFR
  o0 = x0; o1 = x1;
}

__device__ __forceinline__ uint32_t jax_random_bits32(uint32_t flat) {
#if RNG_VARIANT == 1
  uint32_t o0, o1;
  tf2x32(0u, flat, o0, o1);     // counter u64: hi=0 (x0), lo=flat (x1)
  return o0 ^ o1;
#elif RNG_VARIANT == 2
  uint32_t o0, o1;
  tf2x32(0u, flat, o0, o1);
  return o0;
#else
  // legacy: bits = threefry(key, iota(2N)) with iota split in halves
  const uint32_t N = (BB * LLEN * LLEN * 2) / 2;  // 1048576
  uint32_t o0, o1;
  if (flat < N) { tf2x32(flat, flat + N, o0, o1); return o0; }
  else          { tf2x32(flat - N, flat, o0, o1); return o1; }
#endif
}

// jax: u = max(tiny, ((bits>>9)|0x3f800000) - 1.0); g = -log(-log(u))
// NOTE: libm logf (not __logf) — need full relative accuracy for u near 1.
__device__ __forceinline__ float jax_gumbel(uint32_t flat) {
  const uint32_t bits = jax_random_bits32(flat);
  const float f = __uint_as_float((bits >> 9) | 0x3F800000u) - 1.0f;
  const float u = fmaxf(f, 1.17549435e-38f);
  const float L = -logf(u);
  return -logf(L);
}

// tanh via hw exp; abs error ~1e-7, fine for the error budget.
__device__ __forceinline__ float fast_tanh(float x) {
  const float xc = fminf(fmaxf(x, -15.0f), 15.0f);
  const float e = __expf(2.0f * xc);
  return 1.0f - __fdividef(2.0f, e + 1.0f);
}

// ---------------------------------------------------------------------------
// Kernel A: projections.  blocks 0..511 -> Q rows, 512..1023 -> K rows.
// Each block: 4 rows of input staged in LDS; thread h does 256-long dots.
// ---------------------------------------------------------------------------
__global__ __launch_bounds__(128) void proj_kernel(
    const float* __restrict__ queries, const float* __restrict__ keys,
    const float* __restrict__ Wq, const float* __restrict__ Wk,
    float* __restrict__ Qp, float* __restrict__ Kp) {
  const int blk = blockIdx.x;
  const bool isK = blk >= (BB * LLEN / 4);
  const int rb = (isK ? blk - (BB * LLEN / 4) : blk) * 4;  // row base (of 2048)
  const float* __restrict__ in  = isK ? keys : queries;
  const float* __restrict__ W   = isK ? Wk : Wq;
  float* __restrict__ outp      = isK ? Kp : Qp;

  __shared__ float rows[4][DD];
  const float4* in4 = reinterpret_cast<const float4*>(in + (size_t)rb * DD);
  float4* rows4 = reinterpret_cast<float4*>(&rows[0][0]);
  for (int t = threadIdx.x; t < 4 * DD / 4; t += 128) rows4[t] = in4[t];
  __syncthreads();

  const int h = threadIdx.x;
  const float4* W4 = reinterpret_cast<const float4*>(W + (size_t)h * DD);
  float a0 = 0.f, a1 = 0.f, a2 = 0.f, a3 = 0.f;
  #pragma unroll 4
  for (int d4 = 0; d4 < DD / 4; ++d4) {
    const float4 w = W4[d4];
    const int d = d4 * 4;
    a0 = fmaf(w.x, rows[0][d], fmaf(w.y, rows[0][d+1], fmaf(w.z, rows[0][d+2], fmaf(w.w, rows[0][d+3], a0))));
    a1 = fmaf(w.x, rows[1][d], fmaf(w.y, rows[1][d+1], fmaf(w.z, rows[1][d+2], fmaf(w.w, rows[1][d+3], a1))));
    a2 = fmaf(w.x, rows[2][d], fmaf(w.y, rows[2][d+1], fmaf(w.z, rows[2][d+2], fmaf(w.w, rows[2][d+3], a2))));
    a3 = fmaf(w.x, rows[3][d], fmaf(w.y, rows[3][d+1], fmaf(w.z, rows[3][d+2], fmaf(w.w, rows[3][d+3], a3))));
  }
  float* orow = outp + (size_t)rb * HH + h;
  orow[0 * HH] = a0; orow[1 * HH] = a1; orow[2 * HH] = a2; orow[3 * HH] = a3;
}

// ---------------------------------------------------------------------------
// Kernel B: 32x32 output tile per block (grid 16x16x4), 256 threads,
// 4 outputs/thread.  Q/K tiles in LDS as float4 with odd stride 33
// (conflict-free ds_read_b128: 8 consecutive lanes fill all 32 banks).
// ---------------------------------------------------------------------------
__global__ __launch_bounds__(256) void attn_kernel(
    const float* __restrict__ Qp, const float* __restrict__ Kp,
    const int* __restrict__ mask, const float* __restrict__ Wv,
    float* __restrict__ out) {
  __shared__ float4 QL[32][33];
  __shared__ float4 KL[32][33];
  __shared__ float4 WvL[64];  // [0..31]=Wv[0][h], [32..63]=Wv[1][h]

  const int bi = blockIdx.x, bj = blockIdx.y, b = blockIdx.z;
  const int i0 = bi * 32, j0 = bj * 32;

  const float4* Q4 = reinterpret_cast<const float4*>(Qp) + ((size_t)b * LLEN + i0) * (HH / 4);
  const float4* K4 = reinterpret_cast<const float4*>(Kp) + ((size_t)b * LLEN + j0) * (HH / 4);
  for (int t = threadIdx.x; t < 32 * (HH / 4); t += 256) {
    QL[t >> 5][t & 31] = Q4[t];
    KL[t >> 5][t & 31] = K4[t];
  }
  if (threadIdx.x < 64)
    WvL[threadIdx.x] = reinterpret_cast<const float4*>(Wv)[threadIdx.x];
  __syncthreads();

  const int jj = threadIdx.x & 31;   // j within tile
  const int ib = threadIdx.x >> 5;   // i base (0..7); rows ib, ib+8, ib+16, ib+24

  float s0[4] = {0.f, 0.f, 0.f, 0.f};
  float s1[4] = {0.f, 0.f, 0.f, 0.f};

  #pragma unroll 4
  for (int h4 = 0; h4 < HH / 4; ++h4) {
    const float4 kv = KL[jj][h4];
    const float4 w0 = WvL[h4];
    const float4 w1 = WvL[32 + h4];
    #pragma unroll
    for (int r = 0; r < 4; ++r) {
      const float4 qv = QL[ib + 8 * r][h4];
      const float t0 = fast_tanh(qv.x + kv.x);
      const float t1 = fast_tanh(qv.y + kv.y);
      const float t2 = fast_tanh(qv.z + kv.z);
      const float t3 = fast_tanh(qv.w + kv.w);
      s0[r] = fmaf(t0, w0.x, fmaf(t1, w0.y, fmaf(t2, w0.z, fmaf(t3, w0.w, s0[r]))));
      s1[r] = fmaf(t0, w1.x, fmaf(t1, w1.y, fmaf(t2, w1.z, fmaf(t3, w1.w, s1[r]))));
    }
  }

  #pragma unroll
  for (int r = 0; r < 4; ++r) {
    const int i = i0 + ib + 8 * r;
    const int j = j0 + jj;
    const uint32_t idx = ((uint32_t)b * LLEN + i) * LLEN + j;
    const int m = mask[idx];
    const float g0 = jax_gumbel(idx * 2u);
    const float g1 = jax_gumbel(idx * 2u + 1u);
    const float a0 = s0[r] + g0;
    const float a1 = (m >= 2) ? (s1[r] + g1) : (-1000000.0f + g1);
    const float arg = (a0 - a1) * 100.0f;   // (x0 - x1)/tau
    out[idx] = 1.0f / (1.0f + __expf(-arg));  // softmax channel 0
  }
}

extern "C" void kernel_launch(void* const* d_in, const int* in_sizes, int n_in,
                              void* d_out, int out_size, void* d_ws, size_t ws_size,
                              hipStream_t stream) {
  const float* queries = (const float*)d_in[0];
  const float* keys    = (const float*)d_in[1];
  const int*   mask    = (const int*)d_in[2];
  const float* Wq      = (const float*)d_in[3];
  const float* Wk      = (const float*)d_in[4];
  const float* Wv      = (const float*)d_in[5];
  float* out = (float*)d_out;

  // workspace: Qp [2048][128] f32, Kp [2048][128] f32  (2 MB total)
  float* Qp = (float*)d_ws;
  float* Kp = Qp + (size_t)BB * LLEN * HH;

  proj_kernel<<<dim3(2 * (BB * LLEN / 4)), dim3(128), 0, stream>>>(
      queries, keys, Wq, Wk, Qp, Kp);
  attn_kernel<<<dim3(LLEN / 32, LLEN / 32, BB), dim3(256), 0, stream>>>(
      Qp, Kp, mask, Wv, out);
}